// Round 1
// baseline (354.588 us; speedup 1.0000x reference)
//
#include <hip/hip_runtime.h>
#include <stdint.h>

#define D_MODEL 256
#define NHEAD   8
#define HDIM    32
#define BATCH   4
#define SEQ     2048
#define MTOT    (BATCH*SEQ)   // 8192 rows

typedef float f32x4 __attribute__((ext_vector_type(4)));
typedef short s16x8 __attribute__((ext_vector_type(8)));
typedef short s16x4 __attribute__((ext_vector_type(4)));

// fp32 -> bf16 (RNE)
__device__ __forceinline__ unsigned short f2bf(float f) {
    union { float f; uint32_t u; } v; v.f = f;
    uint32_t u = v.u;
    u += 0x7fffu + ((u >> 16) & 1u);
    return (unsigned short)(u >> 16);
}

__device__ __forceinline__ void mfma16(f32x4& c, s16x8 a, s16x8 b) {
    c = __builtin_amdgcn_mfma_f32_16x16x32_bf16(a, b, c, 0, 0, 0);
}

// ---------------------------------------------------------------------------
// Pack mask [B,1,S,S] int32 -> bitmask (1 bit per element). 64 MiB -> 2 MiB.
// One u64 word per 64 consecutive k; bit i == (mask != 0) for lane i.
// ---------------------------------------------------------------------------
__global__ void pack_mask(const int* __restrict__ mask,
                          unsigned long long* __restrict__ pm) {
    const int lane = threadIdx.x & 63;
    const int wid  = (blockIdx.x * blockDim.x + threadIdx.x) >> 6;
    const int nw   = (gridDim.x * blockDim.x) >> 6;
    const int nchunks = BATCH * SEQ * (SEQ / 64);
    for (int c = wid; c < nchunks; c += nw) {
        int v = mask[(size_t)c * 64 + lane];
        unsigned long long bits = __ballot(v != 0);
        if (lane == 0) pm[c] = bits;
    }
}

// ---------------------------------------------------------------------------
// C[M,256] = A[M,256] @ W[256,256]^T + bias.  A fp32 (converted) or bf16.
// BM=BN=64, BK=32; 4 waves in 2x2 grid, each wave 32x32 out (2x2 16x16 frags).
// ---------------------------------------------------------------------------
template<int IN_BF16, int OUT_BF16>
__global__ __launch_bounds__(256)
void gemm_xwT(const void* __restrict__ Av, const float* __restrict__ W,
              const float* __restrict__ bias, void* __restrict__ Cv) {
    __shared__ __align__(16) unsigned short As[64][40];  // +8 pad: conflict-free b128
    __shared__ __align__(16) unsigned short Ws[64][40];
    const int t = threadIdx.x;
    const int lane = t & 63, w = t >> 6;
    const int wm = w >> 1, wn = w & 1;
    const int m0 = blockIdx.x * 64, n0 = blockIdx.y * 64;
    const int fr = lane & 15, fg = lane >> 4;       // frag row / k-group
    const int srow = t >> 2, scol = (t & 3) * 8;    // staging: 64 rows x 32 cols

    f32x4 acc[2][2] = {{{0,0,0,0},{0,0,0,0}},{{0,0,0,0},{0,0,0,0}}};

    for (int k0 = 0; k0 < D_MODEL; k0 += 32) {
        if (IN_BF16) {
            const unsigned short* A = (const unsigned short*)Av;
            *(s16x8*)(&As[srow][scol]) =
                *(const s16x8*)(&A[(size_t)(m0 + srow) * D_MODEL + k0 + scol]);
        } else {
            const float* A = (const float*)Av;
            const float* p = &A[(size_t)(m0 + srow) * D_MODEL + k0 + scol];
            f32x4 x0 = *(const f32x4*)p;
            f32x4 x1 = *(const f32x4*)(p + 4);
            s16x8 v;
            v[0] = (short)f2bf(x0[0]); v[1] = (short)f2bf(x0[1]);
            v[2] = (short)f2bf(x0[2]); v[3] = (short)f2bf(x0[3]);
            v[4] = (short)f2bf(x1[0]); v[5] = (short)f2bf(x1[1]);
            v[6] = (short)f2bf(x1[2]); v[7] = (short)f2bf(x1[3]);
            *(s16x8*)(&As[srow][scol]) = v;
        }
        {
            const float* p = &W[(size_t)(n0 + srow) * D_MODEL + k0 + scol];
            f32x4 x0 = *(const f32x4*)p;
            f32x4 x1 = *(const f32x4*)(p + 4);
            s16x8 v;
            v[0] = (short)f2bf(x0[0]); v[1] = (short)f2bf(x0[1]);
            v[2] = (short)f2bf(x0[2]); v[3] = (short)f2bf(x0[3]);
            v[4] = (short)f2bf(x1[0]); v[5] = (short)f2bf(x1[1]);
            v[6] = (short)f2bf(x1[2]); v[7] = (short)f2bf(x1[3]);
            *(s16x8*)(&Ws[srow][scol]) = v;
        }
        __syncthreads();
        // A-frag: row = m (lane&15), k-chunk = (lane>>4)*8 (contiguous)
        s16x8 a0 = *(const s16x8*)(&As[wm * 32 + fr][fg * 8]);
        s16x8 a1 = *(const s16x8*)(&As[wm * 32 + 16 + fr][fg * 8]);
        // B-frag: col = n (lane&15) -> row of Ws (W[n][k], k contiguous)
        s16x8 b0 = *(const s16x8*)(&Ws[wn * 32 + fr][fg * 8]);
        s16x8 b1 = *(const s16x8*)(&Ws[wn * 32 + 16 + fr][fg * 8]);
        mfma16(acc[0][0], a0, b0);
        mfma16(acc[0][1], a0, b1);
        mfma16(acc[1][0], a1, b0);
        mfma16(acc[1][1], a1, b1);
        __syncthreads();
    }
    // D layout: col = lane&15 = n, row = (lane>>4)*4 + r = m
    for (int mi = 0; mi < 2; ++mi)
        for (int ni = 0; ni < 2; ++ni) {
            const int n = n0 + wn * 32 + ni * 16 + fr;
            const float bn = bias[n];
            #pragma unroll
            for (int r = 0; r < 4; ++r) {
                const int m = m0 + wm * 32 + mi * 16 + fg * 4 + r;
                const float v = acc[mi][ni][r] + bn;
                if (OUT_BF16)
                    ((unsigned short*)Cv)[(size_t)m * D_MODEL + n] = f2bf(v);
                else
                    ((float*)Cv)[(size_t)m * D_MODEL + n] = v;
            }
        }
}

// ---------------------------------------------------------------------------
// Flash attention, one (b,h) per blockIdx.y, 64 q-rows per block (16/wave).
// K-tile = 32 keys. Online softmax in exp2 domain; scale = 1/sqrt(32)*log2(e).
// ---------------------------------------------------------------------------
__global__ __launch_bounds__(256)
void attn_fused(const unsigned short* __restrict__ Qb,
                const unsigned short* __restrict__ Kb,
                const unsigned short* __restrict__ Vb,
                const uint32_t* __restrict__ pmask,
                unsigned short* __restrict__ Ob) {
    __shared__ __align__(16) unsigned short Ks[32][40];      // [key][d]
    __shared__ __align__(16) unsigned short Vt[32][40];      // [d][key]
    __shared__ __align__(16) unsigned short Ps[4][16][40];   // per-wave P tile
    const int t = threadIdx.x, lane = t & 63, w = t >> 6;
    const int b = blockIdx.y >> 3, h = blockIdx.y & 7;
    const int q0 = blockIdx.x * 64 + w * 16;
    const int fr = lane & 15, fg = lane >> 4;
    const float cs = 0.17677669529663687f * 1.4426950408889634f; // 1/sqrt(32)*log2e

    // Q fragment stays in registers: row q0+fr, dims fg*8..fg*8+7
    s16x8 qf = *(const s16x8*)(
        &Qb[((size_t)b * SEQ + q0 + fr) * D_MODEL + h * HDIM + fg * 8]);

    f32x4 acc0 = {0,0,0,0}, acc1 = {0,0,0,0};
    float mrun[4] = {-1e20f,-1e20f,-1e20f,-1e20f};  // floor: all-masked tile -> p=0
    float lrun[4] = {0,0,0,0};

    const int srow = t >> 3, scol = (t & 7) * 4;    // staging: 32 keys x 32 d
    const size_t kvbase = (size_t)b * SEQ * D_MODEL + h * HDIM;

    for (int k0 = 0; k0 < SEQ; k0 += 32) {
        {   // stage K row-major and V transposed
            const size_t g = kvbase + (size_t)(k0 + srow) * D_MODEL + scol;
            s16x4 kv = *(const s16x4*)(&Kb[g]);
            s16x4 vv = *(const s16x4*)(&Vb[g]);
            *(s16x4*)(&Ks[srow][scol]) = kv;
            Vt[scol + 0][srow] = (unsigned short)vv[0];
            Vt[scol + 1][srow] = (unsigned short)vv[1];
            Vt[scol + 2][srow] = (unsigned short)vv[2];
            Vt[scol + 3][srow] = (unsigned short)vv[3];
        }
        __syncthreads();

        // QK^T: B-frag = K^T, lane reads Ks[key=fr][d-chunk] contiguous
        f32x4 s0 = {0,0,0,0}, s1 = {0,0,0,0};
        s16x8 kf0 = *(const s16x8*)(&Ks[fr][fg * 8]);
        s16x8 kf1 = *(const s16x8*)(&Ks[16 + fr][fg * 8]);
        mfma16(s0, qf, kf0);   // rows q = fg*4+r, col key = k0+fr
        mfma16(s1, qf, kf1);   // col key = k0+16+fr

        const int kt = k0 >> 5;
        float sv0[4], sv1[4], mx[4];
        #pragma unroll
        for (int r = 0; r < 4; ++r) {
            const uint32_t mw = pmask[((size_t)b * SEQ + q0 + fg * 4 + r) * 64 + kt];
            sv0[r] = ((mw >> fr)        & 1u) ? s0[r] * cs : -1e30f;
            sv1[r] = ((mw >> (fr + 16)) & 1u) ? s1[r] * cs : -1e30f;
            mx[r] = fmaxf(sv0[r], sv1[r]);
        }
        // row-max across the 16 lanes holding this q's keys
        #pragma unroll
        for (int x = 1; x < 16; x <<= 1)
            #pragma unroll
            for (int r = 0; r < 4; ++r)
                mx[r] = fmaxf(mx[r], __shfl_xor(mx[r], x, 64));

        float pr0[4], pr1[4], rs[4], sm[4];
        #pragma unroll
        for (int r = 0; r < 4; ++r) {
            const float mn = fmaxf(mrun[r], mx[r]);
            rs[r]  = exp2f(mrun[r] - mn);
            mrun[r] = mn;
            pr0[r] = exp2f(sv0[r] - mn);
            pr1[r] = exp2f(sv1[r] - mn);
            sm[r]  = pr0[r] + pr1[r];
        }
        #pragma unroll
        for (int x = 1; x < 16; x <<= 1)
            #pragma unroll
            for (int r = 0; r < 4; ++r)
                sm[r] += __shfl_xor(sm[r], x, 64);

        #pragma unroll
        for (int r = 0; r < 4; ++r) {
            lrun[r] = lrun[r] * rs[r] + sm[r];
            acc0[r] *= rs[r];
            acc1[r] *= rs[r];
            // P (bf16) to per-wave LDS to re-fragment as MFMA A operand.
            Ps[w][fg * 4 + r][fr]      = f2bf(pr0[r]);
            Ps[w][fg * 4 + r][fr + 16] = f2bf(pr1[r]);
        }
        // Same-wave ds ops execute in order; compiler sees the alias -> no barrier.
        s16x8 pa  = *(const s16x8*)(&Ps[w][fr][fg * 8]);          // A: P[q][k-chunk]
        s16x8 vf0 = *(const s16x8*)(&Vt[fr][fg * 8]);             // B: V[k][d=fr]
        s16x8 vf1 = *(const s16x8*)(&Vt[16 + fr][fg * 8]);        // B: d = 16+fr
        mfma16(acc0, pa, vf0);
        mfma16(acc1, pa, vf1);
        __syncthreads();   // before next tile overwrites Ks/Vt
    }

    #pragma unroll
    for (int r = 0; r < 4; ++r) {
        const float inv = 1.0f / lrun[r];
        unsigned short* op =
            &Ob[((size_t)b * SEQ + q0 + fg * 4 + r) * D_MODEL + h * HDIM];
        op[fr]      = f2bf(acc0[r] * inv);
        op[fr + 16] = f2bf(acc1[r] * inv);
    }
}

// ---------------------------------------------------------------------------
extern "C" void kernel_launch(void* const* d_in, const int* in_sizes, int n_in,
                              void* d_out, int out_size, void* d_ws, size_t ws_size,
                              hipStream_t stream) {
    const float* query = (const float*)d_in[0];
    const float* key   = (const float*)d_in[1];
    const float* value = (const float*)d_in[2];
    const int*   mask  = (const int*)  d_in[3];
    const float* Wq = (const float*)d_in[4];   const float* bq = (const float*)d_in[5];
    const float* Wk = (const float*)d_in[6];   const float* bk = (const float*)d_in[7];
    const float* Wv = (const float*)d_in[8];   const float* bv = (const float*)d_in[9];
    const float* Wo = (const float*)d_in[10];  const float* bo = (const float*)d_in[11];

    char* ws = (char*)d_ws;
    unsigned short* Qb = (unsigned short*)(ws);                             // 4 MiB
    unsigned short* Kb = (unsigned short*)(ws + (size_t)4  * 1024 * 1024);  // 4 MiB
    unsigned short* Vb = (unsigned short*)(ws + (size_t)8  * 1024 * 1024);  // 4 MiB
    unsigned short* Ao = (unsigned short*)(ws + (size_t)12 * 1024 * 1024);  // 4 MiB
    unsigned long long* Pm = (unsigned long long*)(ws + (size_t)16 * 1024 * 1024); // 2 MiB

    pack_mask<<<1024, 256, 0, stream>>>(mask, Pm);
    gemm_xwT<0, 1><<<dim3(MTOT / 64, 4), 256, 0, stream>>>(query, Wq, bq, Qb);
    gemm_xwT<0, 1><<<dim3(MTOT / 64, 4), 256, 0, stream>>>(key,   Wk, bk, Kb);
    gemm_xwT<0, 1><<<dim3(MTOT / 64, 4), 256, 0, stream>>>(value, Wv, bv, Vb);
    attn_fused<<<dim3(SEQ / 64, BATCH * NHEAD), 256, 0, stream>>>(
        Qb, Kb, Vb, (const uint32_t*)Pm, Ao);
    gemm_xwT<1, 0><<<dim3(MTOT / 64, 4), 256, 0, stream>>>(Ao, Wo, bo, (float*)d_out);
}

// Round 3
// 243.735 us; speedup vs baseline: 1.4548x; 1.4548x over previous
//
#include <hip/hip_runtime.h>
#include <stdint.h>

#define D_MODEL 256
#define NHEAD   8
#define HDIM    32
#define BATCH   4
#define SEQ     2048
#define MTOT    (BATCH*SEQ)   // 8192 rows

typedef float f32x4 __attribute__((ext_vector_type(4)));
typedef short s16x8 __attribute__((ext_vector_type(8)));

// fp32 -> bf16 (RNE)
__device__ __forceinline__ unsigned short f2bf(float f) {
    union { float f; uint32_t u; } v; v.f = f;
    uint32_t u = v.u;
    u += 0x7fffu + ((u >> 16) & 1u);
    return (unsigned short)(u >> 16);
}

// packed f32x2 -> bf16x2 (lo = a, hi = b)
__device__ __forceinline__ uint32_t cvtpk_bf16(float a, float b) {
    uint32_t r;
    asm("v_cvt_pk_bf16_f32 %0, %1, %2" : "=v"(r) : "v"(a), "v"(b));
    return r;
}

// ---------------------------------------------------------------------------
// prep: fp32 -> bf16 for X (q,k,v) and the 4 weight matrices. Wq is
// pre-scaled by csc = (1/sqrt(32))*log2(e) so attention scores come out in
// the exp2 domain with no per-element multiply.
// ---------------------------------------------------------------------------
__global__ __launch_bounds__(256)
void prep(const float* __restrict__ q, const float* __restrict__ k, const float* __restrict__ v,
          const float* __restrict__ wq, const float* __restrict__ wk,
          const float* __restrict__ wv, const float* __restrict__ wo,
          unsigned short* __restrict__ qb, unsigned short* __restrict__ kb,
          unsigned short* __restrict__ vb,
          unsigned short* __restrict__ wqb, unsigned short* __restrict__ wkb,
          unsigned short* __restrict__ wvb, unsigned short* __restrict__ wob, float csc) {
    const int y = blockIdx.y;
    const float* src; unsigned short* dst; int n; float sc = 1.0f;
    switch (y) {
        case 0:  src = q;  dst = qb;  n = MTOT * 256; break;
        case 1:  src = k;  dst = kb;  n = MTOT * 256; break;
        case 2:  src = v;  dst = vb;  n = MTOT * 256; break;
        case 3:  src = wq; dst = wqb; n = 65536; sc = csc; break;
        case 4:  src = wk; dst = wkb; n = 65536; break;
        case 5:  src = wv; dst = wvb; n = 65536; break;
        default: src = wo; dst = wob; n = 65536; break;
    }
    const int i = (blockIdx.x * 256 + threadIdx.x) * 4;
    if (i >= n) return;
    f32x4 x = *(const f32x4*)(src + i);
    ushort4 o;
    o.x = f2bf(x[0] * sc); o.y = f2bf(x[1] * sc);
    o.z = f2bf(x[2] * sc); o.w = f2bf(x[3] * sc);
    *(ushort4*)(dst + i) = o;
}

// ---------------------------------------------------------------------------
// Pack mask [B,1,S,S] int32 -> bitmask. One u64 per (b, q, 64-key chunk).
// ---------------------------------------------------------------------------
__global__ void pack_mask(const int* __restrict__ mask,
                          unsigned long long* __restrict__ pm) {
    const int lane = threadIdx.x & 63;
    const int wid  = (blockIdx.x * blockDim.x + threadIdx.x) >> 6;
    const int nw   = (gridDim.x * blockDim.x) >> 6;
    const int nchunks = BATCH * SEQ * (SEQ / 64);
    for (int c = wid; c < nchunks; c += nw) {
        int v = mask[(size_t)c * 64 + lane];
        unsigned long long bits = __ballot(v != 0);
        if (lane == 0) pm[c] = bits;
    }
}

// ---------------------------------------------------------------------------
// Fused Q/K/V projections. No LDS: MFMA fragments loaded per-lane direct
// from global (all 16B contiguous).  y=0: Q (transposed-compute -> [b][h][s][d],
// bias scaled by csc), y=1: K (same layout), y=2: V (normal compute ->
// transposed per-head output [b][h][d][s]).
// Block: 32 m-rows x 256 n; 4 waves, wave w owns n in [w*64, w*64+64).
// ---------------------------------------------------------------------------
__global__ __launch_bounds__(256, 3)
void proj3(const unsigned short* __restrict__ Xq, const unsigned short* __restrict__ Xk,
           const unsigned short* __restrict__ Xv,
           const unsigned short* __restrict__ Wqb, const unsigned short* __restrict__ Wkb,
           const unsigned short* __restrict__ Wvb,
           const float* __restrict__ bq, const float* __restrict__ bk,
           const float* __restrict__ bv,
           unsigned short* __restrict__ Qh, unsigned short* __restrict__ Kh,
           unsigned short* __restrict__ Vt, float csc) {
    const int y = blockIdx.y;
    const unsigned short* X = (y == 0) ? Xq : (y == 1) ? Xk : Xv;
    const unsigned short* W = (y == 0) ? Wqb : (y == 1) ? Wkb : Wvb;
    const float* bias = (y == 0) ? bq : (y == 1) ? bk : bv;
    const float bscale = (y == 0) ? csc : 1.0f;

    const int t = threadIdx.x, lane = t & 63, w = t >> 6;
    const int fr = lane & 15, fg = lane >> 4;
    const int m0 = blockIdx.x * 32;
    const int n0w = w * 64;

    f32x4 acc[2][4] = {};

    if (y < 2) {
        // transposed compute: D[n][m] = W . X^T
        #pragma unroll 2
        for (int k0 = 0; k0 < 256; k0 += 32) {
            s16x8 xf[2], wf[4];
            #pragma unroll
            for (int mg = 0; mg < 2; ++mg)
                xf[mg] = *(const s16x8*)(X + ((size_t)(m0 + mg*16 + fr) << 8) + k0 + (fg << 3));
            #pragma unroll
            for (int ng = 0; ng < 4; ++ng)
                wf[ng] = *(const s16x8*)(W + ((size_t)(n0w + ng*16 + fr) << 8) + k0 + (fg << 3));
            #pragma unroll
            for (int mg = 0; mg < 2; ++mg)
                #pragma unroll
                for (int ng = 0; ng < 4; ++ng)
                    acc[mg][ng] = __builtin_amdgcn_mfma_f32_16x16x32_bf16(
                        wf[ng], xf[mg], acc[mg][ng], 0, 0, 0);
        }
        unsigned short* OUT = (y == 0) ? Qh : Kh;
        #pragma unroll
        for (int mg = 0; mg < 2; ++mg) {
            const int m = m0 + mg*16 + fr;          // D col = m
            const int bb = m >> 11, ss = m & 2047;
            #pragma unroll
            for (int ng = 0; ng < 4; ++ng) {
                const int nb = n0w + ng*16 + fg*4;   // D rows = n (4 consecutive)
                const int hh = nb >> 5, db = nb & 31;
                f32x4 bi = *(const f32x4*)(bias + nb);
                ushort4 o;
                o.x = f2bf(acc[mg][ng][0] + bi[0] * bscale);
                o.y = f2bf(acc[mg][ng][1] + bi[1] * bscale);
                o.z = f2bf(acc[mg][ng][2] + bi[2] * bscale);
                o.w = f2bf(acc[mg][ng][3] + bi[3] * bscale);
                *(ushort4*)(OUT + (((size_t)(bb*8 + hh) * SEQ) + ss) * 32 + db) = o;
            }
        }
    } else {
        // normal compute: D[m][n] = X . W^T -> store transposed per head
        #pragma unroll 2
        for (int k0 = 0; k0 < 256; k0 += 32) {
            s16x8 xf[2], wf[4];
            #pragma unroll
            for (int mg = 0; mg < 2; ++mg)
                xf[mg] = *(const s16x8*)(X + ((size_t)(m0 + mg*16 + fr) << 8) + k0 + (fg << 3));
            #pragma unroll
            for (int ng = 0; ng < 4; ++ng)
                wf[ng] = *(const s16x8*)(W + ((size_t)(n0w + ng*16 + fr) << 8) + k0 + (fg << 3));
            #pragma unroll
            for (int mg = 0; mg < 2; ++mg)
                #pragma unroll
                for (int ng = 0; ng < 4; ++ng)
                    acc[mg][ng] = __builtin_amdgcn_mfma_f32_16x16x32_bf16(
                        xf[mg], wf[ng], acc[mg][ng], 0, 0, 0);
        }
        #pragma unroll
        for (int mg = 0; mg < 2; ++mg) {
            const int sb = m0 + mg*16 + fg*4;        // D rows = m (4 consecutive s)
            const int bb = sb >> 11, ss = sb & 2047;
            #pragma unroll
            for (int ng = 0; ng < 4; ++ng) {
                const int n = n0w + ng*16 + fr;      // D col = n
                const int hh = n >> 5, dd = n & 31;
                const float bi = bias[n];
                ushort4 o;
                o.x = f2bf(acc[mg][ng][0] + bi);
                o.y = f2bf(acc[mg][ng][1] + bi);
                o.z = f2bf(acc[mg][ng][2] + bi);
                o.w = f2bf(acc[mg][ng][3] + bi);
                *(ushort4*)(Vt + (((size_t)(bb*8 + hh) * 32) + dd) * SEQ + ss) = o;
            }
        }
    }
}

// ---------------------------------------------------------------------------
// Output projection: d_out[m][n] = Ao . Wo^T + bo (fp32 out, transposed
// compute so each lane stores a contiguous f32x4).
// ---------------------------------------------------------------------------
__global__ __launch_bounds__(256, 3)
void oproj(const unsigned short* __restrict__ Ao, const unsigned short* __restrict__ Wo,
           const float* __restrict__ bo, float* __restrict__ out) {
    const int t = threadIdx.x, lane = t & 63, w = t >> 6;
    const int fr = lane & 15, fg = lane >> 4;
    const int m0 = blockIdx.x * 32;
    const int n0w = w * 64;

    f32x4 acc[2][4] = {};
    #pragma unroll 2
    for (int k0 = 0; k0 < 256; k0 += 32) {
        s16x8 xf[2], wf[4];
        #pragma unroll
        for (int mg = 0; mg < 2; ++mg)
            xf[mg] = *(const s16x8*)(Ao + ((size_t)(m0 + mg*16 + fr) << 8) + k0 + (fg << 3));
        #pragma unroll
        for (int ng = 0; ng < 4; ++ng)
            wf[ng] = *(const s16x8*)(Wo + ((size_t)(n0w + ng*16 + fr) << 8) + k0 + (fg << 3));
        #pragma unroll
        for (int mg = 0; mg < 2; ++mg)
            #pragma unroll
            for (int ng = 0; ng < 4; ++ng)
                acc[mg][ng] = __builtin_amdgcn_mfma_f32_16x16x32_bf16(
                    wf[ng], xf[mg], acc[mg][ng], 0, 0, 0);
    }
    #pragma unroll
    for (int mg = 0; mg < 2; ++mg) {
        const int m = m0 + mg*16 + fr;
        #pragma unroll
        for (int ng = 0; ng < 4; ++ng) {
            const int nb = n0w + ng*16 + fg*4;
            f32x4 bi = *(const f32x4*)(bo + nb);
            f32x4 vv = acc[mg][ng] + bi;
            *(f32x4*)(out + (size_t)m * 256 + nb) = vv;
        }
    }
}

// ---------------------------------------------------------------------------
// Flash attention, swapped-QK layout, no block-level sync, no K/V LDS.
// Wave owns 32 q-rows (2 groups of 16); KV tile = 64 keys.
// S^T = K.Q^T via mfma (mask folded into the C operand), softmax reduction
// is in-lane + 2 shfls, P goes through a per-wave XOR-swizzled LDS buffer
// to re-fragment, O^T = V^T.P^T via mfma.
// ---------------------------------------------------------------------------
struct TR {
    s16x8 kf[4];
    s16x8 vf[2][2];
    unsigned long long mw[2];
};

__device__ __forceinline__ void load_tile(TR& tr, int ti,
        const unsigned short* Kb, const unsigned short* Vb,
        const unsigned long long* pm0, const unsigned long long* pm1,
        int fr, int fg) {
    tr.mw[0] = pm0[ti];
    tr.mw[1] = pm1[ti];
    #pragma unroll
    for (int g = 0; g < 4; ++g)   // A-frag rows = keys ti*64+g*16+fr
        tr.kf[g] = *(const s16x8*)(Kb + ((ti*64 + g*16 + fr) << 5) + (fg << 3));
    #pragma unroll
    for (int c = 0; c < 2; ++c)   // A-frag rows = dims hh*16+fr, k = keys c*32+fg*8
        #pragma unroll
        for (int hh = 0; hh < 2; ++hh)
            tr.vf[c][hh] = *(const s16x8*)(Vb + ((hh*16 + fr) << 11) + ti*64 + c*32 + (fg << 3));
}

__device__ __forceinline__ void compute_tile(const TR& tr, const s16x8* qf,
        f32x4 acc[2][2], float* mrun, float* lrun, char* ptb, int fr, int fg) {
    #pragma unroll
    for (int j = 0; j < 2; ++j) {
        const unsigned long long wsh = tr.mw[j] >> (fg * 4);
        const uint32_t wlo = (uint32_t)wsh, whi = (uint32_t)(wsh >> 32);
        f32x4 s[4];
        #pragma unroll
        for (int g = 0; g < 4; ++g) {
            const uint32_t wsel = (g < 2) ? wlo : whi;
            f32x4 cm;   // additive mask folded into the MFMA C operand
            #pragma unroll
            for (int r = 0; r < 4; ++r)
                cm[r] = ((wsel >> ((g & 1) * 16 + r)) & 1u) ? 0.0f : -1.0e30f;
            s[g] = __builtin_amdgcn_mfma_f32_16x16x32_bf16(tr.kf[g], qf[j], cm, 0, 0, 0);
        }
        float v[16];
        #pragma unroll
        for (int g = 0; g < 4; ++g)
            #pragma unroll
            for (int r = 0; r < 4; ++r)
                v[g*4 + r] = s[g][r];
        // row max: in-lane tree + 2 cross-fg shuffles
        float t8[8];
        #pragma unroll
        for (int i = 0; i < 8; ++i) t8[i] = fmaxf(v[2*i], v[2*i+1]);
        float mx = fmaxf(fmaxf(fmaxf(t8[0], t8[1]), fmaxf(t8[2], t8[3])),
                         fmaxf(fmaxf(t8[4], t8[5]), fmaxf(t8[6], t8[7])));
        mx = fmaxf(mx, __shfl_xor(mx, 16));
        mx = fmaxf(mx, __shfl_xor(mx, 32));
        const float mn = fmaxf(mrun[j], mx);   // floor -1e20 keeps all-masked tiles inert
        const float rs = exp2f(mrun[j] - mn);
        mrun[j] = mn;
        float p[16];
        #pragma unroll
        for (int i = 0; i < 16; ++i) p[i] = exp2f(v[i] - mn);
        float s8[8];
        #pragma unroll
        for (int i = 0; i < 8; ++i) s8[i] = p[2*i] + p[2*i+1];
        float sum = ((s8[0]+s8[1]) + (s8[2]+s8[3])) + ((s8[4]+s8[5]) + (s8[6]+s8[7]));
        sum += __shfl_xor(sum, 16);
        sum += __shfl_xor(sum, 32);
        lrun[j] = lrun[j] * rs + sum;
        acc[j][0] *= rs;
        acc[j][1] *= rs;
        // P -> per-wave LDS (XOR-swizzled 128B rows), re-read as B-frags.
        // Same-wave DS ops complete in order; no barrier needed.
        char* row = ptb + (j << 11) + fr * 128;
        #pragma unroll
        for (int g = 0; g < 4; ++g) {
            const uint32_t p0 = cvtpk_bf16(p[g*4+0], p[g*4+1]);
            const uint32_t p1 = cvtpk_bf16(p[g*4+2], p[g*4+3]);
            const int slot = (g*2 + (fg >> 1)) ^ (fr & 7);
            *(uint2*)(row + (slot << 4) + ((fg & 1) << 3)) = make_uint2(p0, p1);
        }
        #pragma unroll
        for (int c = 0; c < 2; ++c) {
            const int slot = (c*4 + fg) ^ (fr & 7);
            const s16x8 pb = *(const s16x8*)(row + (slot << 4));
            #pragma unroll
            for (int hh = 0; hh < 2; ++hh)
                acc[j][hh] = __builtin_amdgcn_mfma_f32_16x16x32_bf16(
                    tr.vf[c][hh], pb, acc[j][hh], 0, 0, 0);
        }
    }
}

__global__ __launch_bounds__(256, 2)
void attn_fused(const unsigned short* __restrict__ Qh,
                const unsigned short* __restrict__ Kh,
                const unsigned short* __restrict__ Vt,
                const unsigned long long* __restrict__ pm,
                unsigned short* __restrict__ Ao) {
    __shared__ __align__(16) char ptbuf[16384];   // 4KB per wave (2 q-groups x 2KB)
    const int t = threadIdx.x, lane = t & 63, w = t >> 6;
    const int fr = lane & 15, fg = lane >> 4;
    const int by = blockIdx.y, b = by >> 3, h = by & 7;
    const int q0 = blockIdx.x * 128 + w * 32;
    const unsigned short* Qb = Qh + (size_t)by * SEQ * HDIM;
    const unsigned short* Kb = Kh + (size_t)by * SEQ * HDIM;
    const unsigned short* Vb = Vt + (size_t)by * HDIM * SEQ;
    const unsigned long long* pm0 = pm + ((size_t)b * SEQ + q0 + fr) * 32;
    const unsigned long long* pm1 = pm0 + 16 * 32;
    char* ptb = ptbuf + (w << 12);

    s16x8 qf[2];   // B-frag: col=q, k=d
    #pragma unroll
    for (int j = 0; j < 2; ++j)
        qf[j] = *(const s16x8*)(Qb + ((q0 + j*16 + fr) << 5) + (fg << 3));

    f32x4 acc[2][2] = {};
    float mrun[2] = {-1e20f, -1e20f};
    float lrun[2] = {0.0f, 0.0f};

    TR A, B;
    load_tile(A, 0, Kb, Vb, pm0, pm1, fr, fg);
    #pragma unroll 1
    for (int ti = 0; ti < 32; ti += 2) {
        load_tile(B, ti + 1, Kb, Vb, pm0, pm1, fr, fg);
        compute_tile(A, qf, acc, mrun, lrun, ptb, fr, fg);
        load_tile(A, (ti + 2 < 32) ? ti + 2 : 31, Kb, Vb, pm0, pm1, fr, fg);
        compute_tile(B, qf, acc, mrun, lrun, ptb, fr, fg);
    }

    #pragma unroll
    for (int j = 0; j < 2; ++j) {
        const float inv = 1.0f / lrun[j];
        const int q = q0 + j*16 + fr;
        #pragma unroll
        for (int hh = 0; hh < 2; ++hh) {
            ushort4 o;
            o.x = f2bf(acc[j][hh][0] * inv);
            o.y = f2bf(acc[j][hh][1] * inv);
            o.z = f2bf(acc[j][hh][2] * inv);
            o.w = f2bf(acc[j][hh][3] * inv);
            *(ushort4*)(Ao + (((size_t)b * SEQ + q) * 8 + h) * 32 + hh*16 + fg*4) = o;
        }
    }
}

// ---------------------------------------------------------------------------
extern "C" void kernel_launch(void* const* d_in, const int* in_sizes, int n_in,
                              void* d_out, int out_size, void* d_ws, size_t ws_size,
                              hipStream_t stream) {
    const float* query = (const float*)d_in[0];
    const float* key   = (const float*)d_in[1];
    const float* value = (const float*)d_in[2];
    const int*   mask  = (const int*)  d_in[3];
    const float* Wq = (const float*)d_in[4];   const float* bq = (const float*)d_in[5];
    const float* Wk = (const float*)d_in[6];   const float* bk = (const float*)d_in[7];
    const float* Wv = (const float*)d_in[8];   const float* bv = (const float*)d_in[9];
    const float* Wo = (const float*)d_in[10];  const float* bo = (const float*)d_in[11];

    char* ws = (char*)d_ws;
    const size_t MB = 1024 * 1024;
    unsigned short* qbf = (unsigned short*)(ws);
    unsigned short* kbf = (unsigned short*)(ws + 4*MB);
    unsigned short* vbf = (unsigned short*)(ws + 8*MB);
    unsigned short* wqb = (unsigned short*)(ws + 12*MB);
    unsigned short* wkb = (unsigned short*)(ws + 12*MB + 131072);
    unsigned short* wvb = (unsigned short*)(ws + 12*MB + 262144);
    unsigned short* wob = (unsigned short*)(ws + 12*MB + 393216);
    unsigned long long* pmw = (unsigned long long*)(ws + 12*MB + 524288);  // 2 MiB
    unsigned short* Qh = (unsigned short*)(ws + 14*MB + 524288);
    unsigned short* Kh = (unsigned short*)(ws + 18*MB + 524288);
    unsigned short* Vt = (unsigned short*)(ws + 22*MB + 524288);
    unsigned short* Aob = (unsigned short*)(ws);   // reuse qbf (dead after proj3)

    const float csc = (float)(0.17677669529663687 * 1.4426950408889634); // log2e/sqrt(32)

    prep<<<dim3(2048, 7), 256, 0, stream>>>(query, key, value, Wq, Wk, Wv, Wo,
                                            qbf, kbf, vbf, wqb, wkb, wvb, wob, csc);
    pack_mask<<<2048, 256, 0, stream>>>(mask, pmw);
    proj3<<<dim3(256, 3), 256, 0, stream>>>(qbf, kbf, vbf, wqb, wkb, wvb,
                                            bq, bk, bv, Qh, Kh, Vt, csc);
    attn_fused<<<dim3(16, 32), 256, 0, stream>>>(Qh, Kh, Vt, pmw, Aob);
    oproj<<<dim3(256), 256, 0, stream>>>(Aob, wob, bo, (float*)d_out);
}